// Round 10
// baseline (73.341 us; speedup 1.0000x reference)
//
#include <hip/hip_runtime.h>
#include <math.h>

#define DIM 4096

// 512 threads/block (8 waves), one block per state, packed-FP32 complex math.
// 4 blocks/CU x 512 = 2048 threads/CU (hardware max) vs 1024 for the 256-thr
// version -- the 32 KB LDS state buffer is per-state, so bigger blocks double
// the occupancy ceiling at +8% pk-instruction cost.
// Amp index i = t*8 + j:
//   j bits 2..0    = i bits 2..0  = wires 9..11 -> in-register butterflies
//   lane bits 5..0 = i bits 8..3  = wires 3..8  -> cross-lane gates
//       masks 1,2,8 -> 1 DPP op; mask 4 -> 2 DPP ops (VALU)
//       masks 16,32 -> ds_swizzle / ds_bpermute (DS crossbar, select-free)
//   wave bits t8..t6 = i bits 11..9 = wires 0..2 -> fused with CNOT chain
//       sigma(i)=i^(i>>1) into one LDS 8-partner gather, coeffs = G0*G1*G2
//       (wave-uniform), partner slots base + y*512.
// LDS slot swizzle S(x) = x ^ h4((x>>4)&15), h4 = inverse Gray map; both the
// b64 write (bank-pair = l0^h4(l4..l1)^j, unitriangular) and the sigma-gather
// read (rank-4 over t3..t0) are bank-conflict-free per 16-lane group.

typedef float f2 __attribute__((ext_vector_type(2)));

// ---- packed complex primitives (VOP3P op_sel/neg; verified R9) ----
// acc += c*v
__device__ __forceinline__ f2 cfma(f2 acc, f2 c, f2 v) {
  asm("v_pk_fma_f32 %0, %1, %2, %0 op_sel:[0,0,0] op_sel_hi:[0,1,1]\n\t"
      "v_pk_fma_f32 %0, %1, %2, %0 op_sel:[1,1,0] op_sel_hi:[1,0,1] neg_lo:[1,0,0]"
      : "+&v"(acc) : "v"(c), "v"(v));
  return acc;
}
// acc += conj(c)*v
__device__ __forceinline__ f2 cfma_cj(f2 acc, f2 c, f2 v) {
  asm("v_pk_fma_f32 %0, %1, %2, %0 op_sel:[0,0,0] op_sel_hi:[0,1,1]\n\t"
      "v_pk_fma_f32 %0, %1, %2, %0 op_sel:[1,1,0] op_sel_hi:[1,0,1] neg_hi:[1,0,0]"
      : "+&v"(acc) : "v"(c), "v"(v));
  return acc;
}
// d = c*v
__device__ __forceinline__ f2 cmul(f2 c, f2 v) {
  f2 d;
  asm("v_pk_mul_f32 %0, %1, %2 op_sel:[0,0] op_sel_hi:[0,1]\n\t"
      "v_pk_fma_f32 %0, %1, %2, %0 op_sel:[1,1,0] op_sel_hi:[1,0,1] neg_lo:[1,0,0]"
      : "=&v"(d) : "v"(c), "v"(v));
  return d;
}
// d = -conj(c)*v
__device__ __forceinline__ f2 cmul_ncj(f2 c, f2 v) {
  f2 d;
  asm("v_pk_mul_f32 %0, %1, %2 op_sel:[0,0] op_sel_hi:[0,1] neg_lo:[1,0] neg_hi:[1,0]\n\t"
      "v_pk_fma_f32 %0, %1, %2, %0 op_sel:[1,1,0] op_sel_hi:[1,0,1] neg_lo:[1,0,0]"
      : "=&v"(d) : "v"(c), "v"(v));
  return d;
}

__device__ __forceinline__ int h4(int x) {
  return (x ^ (x >> 1) ^ (x >> 2) ^ (x >> 3)) & 15;
}

// Cross-lane exchange of x with lane^M partner.
template<int M>
__device__ __forceinline__ float xch(float x, int paddr) {
  int xi = __float_as_int(x);
  if constexpr (M == 1) {        // quad_perm [1,0,3,2]
    return __int_as_float(__builtin_amdgcn_mov_dpp(xi, 0xB1, 0xF, 0xF, false));
  } else if constexpr (M == 2) { // quad_perm [2,3,0,1]
    return __int_as_float(__builtin_amdgcn_mov_dpp(xi, 0x4E, 0xF, 0xF, false));
  } else if constexpr (M == 4) {
    // banks 0,2 need src[i+4] -> row_shl:4; banks 1,3 need src[i-4] -> row_shr:4
    int r = __builtin_amdgcn_update_dpp(xi, xi, 0x104, 0xF, 0x5, false);
    r     = __builtin_amdgcn_update_dpp(r,  xi, 0x114, 0xF, 0xA, false);
    return __int_as_float(r);
  } else if constexpr (M == 8) { // row_ror:8 == xor 8 within 16-lane row
    return __int_as_float(__builtin_amdgcn_mov_dpp(xi, 0x128, 0xF, 0xF, false));
  } else if constexpr (M == 16) { // xor-16 via LDS crossbar (BitMode)
    return __int_as_float(__builtin_amdgcn_ds_swizzle(xi, 0x401F));
  } else {                       // M == 32: cross-half via bpermute
    return __int_as_float(__builtin_amdgcn_ds_bpermute(paddr, xi));
  }
}

template<int M>
__device__ __forceinline__ void lane_gate(float4 g, int t, int paddr,
                                          f2* __restrict__ z) {
  const bool hi = (t & M) != 0;
  const float sgn = hi ? -1.f : 1.f;
  const f2 c1 = { g.x, sgn * g.y };
  const f2 c2 = { sgn * g.z, g.w };
  #pragma unroll
  for (int p = 0; p < 8; ++p) {
    f2 pp;
    pp.x = xch<M>(z[p].x, paddr);
    pp.y = xch<M>(z[p].y, paddr);
    z[p] = cfma(cmul(c1, z[p]), c2, pp);
  }
}

__global__ __launch_bounds__(512)
void qsim_kernel(const float* __restrict__ in, const float* __restrict__ params,
                 const float* __restrict__ hw, const float* __restrict__ hb,
                 float* __restrict__ out) {
  __shared__ f2 st2[DIM];        // 32 KB, swizzled slots
  __shared__ float4 ga4[36];     // fused RZ@RY@RX: (a.re, a.im, b.re, b.im)
  __shared__ float red[8];

  const int t = threadIdx.x;
  const int b = blockIdx.x;

  // Fused gate matrices M = RZ@RY@RX = [[a,b],[-conj(b),conj(a)]]
  if (t < 36) {
    const float* P = params + t * 3;
    float hx = P[0]*0.5f, hy = P[1]*0.5f, hz = P[2]*0.5f;
    float cx = cosf(hx), sx = sinf(hx);
    float cy = cosf(hy), sy = sinf(hy);
    float cz = cosf(hz), sz = sinf(hz);
    float arr = cy*cx, aii = sy*sx, brr = sy*cx, bii = cy*sx;
    ga4[t] = make_float4(cz*arr + sz*aii,
                         cz*aii - sz*arr,
                         -(cz*brr + sz*bii),
                         -(cz*bii - sz*brr));
  }

  // ---- load 8 consecutive amps + block-wide norm ----
  float ld[8];
  const float* inb = in + (size_t)b * DIM + t * 8;
  float ss = 0.f;
  #pragma unroll
  for (int q = 0; q < 2; ++q) {
    float4 v = reinterpret_cast<const float4*>(inb)[q];
    ld[4*q+0]=v.x; ld[4*q+1]=v.y; ld[4*q+2]=v.z; ld[4*q+3]=v.w;
    ss += v.x*v.x + v.y*v.y + v.z*v.z + v.w*v.w;
  }
  #pragma unroll
  for (int o = 1; o < 64; o <<= 1) ss += __shfl_xor(ss, o, 64);
  if ((t & 63) == 0) red[t >> 6] = ss;
  __syncthreads();               // also publishes ga4
  float inv = 1.0f / sqrtf(red[0]+red[1]+red[2]+red[3]+red[4]+red[5]+red[6]+red[7]);
  f2 z[8];
  #pragma unroll
  for (int j = 0; j < 8; ++j) z[j] = (f2){ ld[j] * inv, 0.f };

  // thread-constant addressing (all GF(2)-linear in i)
  const int wbase = (t << 3) ^ h4((t >> 1) & 15);   // write slot = wbase ^ j
  const int sig0  = (t << 3) ^ (t << 2);            // sigma(i) for j=0
  const int sigc  = sig0 & 511;                     // bits 11..9 cleared
  const int gb    = sigc ^ h4((sigc >> 4) & 15);    // gather slot = gb ^ gray3(j) + y*512
  const int x11   = (t >> 8) & 1;                   // sigma(i) bit 11 (wire 0)
  const int x10   = ((t >> 7) ^ (t >> 8)) & 1;      // sigma(i) bit 10 (wire 1)
  const int x9    = ((t >> 6) ^ (t >> 7)) & 1;      // sigma(i) bit  9 (wire 2)
  const int paddr = ((t ^ 32) & 63) << 2;           // bpermute addr for mask 32

  #pragma unroll 1
  for (int L = 0; L < 3; ++L) {
    // ---- 3 register gates: wires 9..11, mask on j (packed butterflies) ----
    #pragma unroll
    for (int w = 9; w <= 11; ++w) {
      const int m = 1 << (11 - w);
      float4 g = ga4[L*12 + w];
      const f2 a  = { g.x, g.y };
      const f2 bb = { g.z, g.w };
      #pragma unroll
      for (int p = 0; p < 8; ++p) {
        if (!(p & m)) {
          const int k2 = p | m;
          f2 v0 = z[p], v1 = z[k2];
          z[p]  = cfma(cmul(a, v0), bb, v1);        // a*v0 + b*v1
          z[k2] = cfma_cj(cmul_ncj(bb, v0), a, v1); // -conj(b)*v0 + conj(a)*v1
        }
      }
    }
    // ---- 6 lane gates: wires 3..8 -> masks 32,16,8,4,2,1 ----
    lane_gate<32>(ga4[L*12 + 3], t, paddr, z);
    lane_gate<16>(ga4[L*12 + 4], t, paddr, z);
    lane_gate< 8>(ga4[L*12 + 5], t, paddr, z);
    lane_gate< 4>(ga4[L*12 + 6], t, paddr, z);
    lane_gate< 2>(ga4[L*12 + 7], t, paddr, z);
    lane_gate< 1>(ga4[L*12 + 8], t, paddr, z);

    // ---- write post-(wires 3..11) state (conflict-free swizzled) ----
    #pragma unroll
    for (int j = 0; j < 8; ++j) st2[wbase ^ j] = z[j];
    __syncthreads();

    // ---- fused: wave gates (wires 0,1,2) + CNOT chain, 8-partner gather ----
    // new[i] = sum_y G0[x11][y2]*G1[x10][y1]*G2[x9][y0]
    //                * mid[sigma(i) w/ bits 11,10,9 := y]
    float4 g0 = ga4[L*12 + 0], g1 = ga4[L*12 + 1], g2 = ga4[L*12 + 2];
    f2 U0, U1, V0, V1, W0, W1;
    if (x11) { U0 = (f2){-g0.z, g0.w}; U1 = (f2){g0.x, -g0.y}; }
    else     { U0 = (f2){ g0.x, g0.y}; U1 = (f2){g0.z,  g0.w}; }
    if (x10) { V0 = (f2){-g1.z, g1.w}; V1 = (f2){g1.x, -g1.y}; }
    else     { V0 = (f2){ g1.x, g1.y}; V1 = (f2){g1.z,  g1.w}; }
    if (x9)  { W0 = (f2){-g2.z, g2.w}; W1 = (f2){g2.x, -g2.y}; }
    else     { W0 = (f2){ g2.x, g2.y}; W1 = (f2){g2.z,  g2.w}; }
    f2 uv00 = cmul(U0, V0), uv01 = cmul(U0, V1);
    f2 uv10 = cmul(U1, V0), uv11 = cmul(U1, V1);
    f2 c0 = cmul(uv00, W0), c1 = cmul(uv00, W1);
    f2 c2 = cmul(uv01, W0), c3 = cmul(uv01, W1);
    f2 c4 = cmul(uv10, W0), c5 = cmul(uv10, W1);
    f2 c6 = cmul(uv11, W0), c7 = cmul(uv11, W1);
    #pragma unroll
    for (int j = 0; j < 8; ++j) {
      const int base = gb ^ (j ^ (j >> 1));
      f2 m0 = st2[base];
      f2 m1 = st2[base +  512];
      f2 m2 = st2[base + 1024];
      f2 m3 = st2[base + 1536];
      f2 m4 = st2[base + 2048];
      f2 m5 = st2[base + 2560];
      f2 m6 = st2[base + 3072];
      f2 m7 = st2[base + 3584];
      f2 a1 = cfma(cfma(cfma(cmul(c0, m0), c1, m1), c2, m2), c3, m3);
      f2 a2 = cfma(cfma(cfma(cmul(c4, m4), c5, m5), c6, m6), c7, m7);
      z[j] = a1 + a2;
    }
    if (L != 2) __syncthreads();  // WAR guard; not needed after last gather
  }

  // ---- readout: sum |amp|^2 * c(i), i = t*8 + j (regs hold final state) ----
  float Ct = 0.f;
  #pragma unroll
  for (int p = 0; p < 9; ++p) Ct += hw[8-p] * (((t >> p) & 1) ? -1.f : 1.f);
  float h9 = hw[9], h10 = hw[10], h11 = hw[11];
  float acc = 0.f;
  #pragma unroll
  for (int j = 0; j < 8; ++j) {
    float pj = z[j].x*z[j].x + z[j].y*z[j].y;
    float cj = Ct + ((j&4) ? -h9 : h9) + ((j&2) ? -h10 : h10)
             + ((j&1) ? -h11 : h11);
    acc += pj * cj;
  }
  #pragma unroll
  for (int o = 1; o < 64; o <<= 1) acc += __shfl_xor(acc, o, 64);
  if ((t & 63) == 0) red[t >> 6] = acc;
  __syncthreads();
  if (t == 0)
    out[b] = red[0]+red[1]+red[2]+red[3]+red[4]+red[5]+red[6]+red[7] + hb[0];
}

extern "C" void kernel_launch(void* const* d_in, const int* in_sizes, int n_in,
                              void* d_out, int out_size, void* d_ws, size_t ws_size,
                              hipStream_t stream) {
  const float* st     = (const float*)d_in[0];
  const float* params = (const float*)d_in[1];
  const float* hwp    = (const float*)d_in[2];
  const float* hbp    = (const float*)d_in[3];
  float* outp = (float*)d_out;
  int batch = in_sizes[0] / DIM;
  qsim_kernel<<<batch, 512, 0, stream>>>(st, params, hwp, hbp, outp);
}

// Round 11
// 68.025 us; speedup vs baseline: 1.0781x; 1.0781x over previous
//
#include <hip/hip_runtime.h>
#include <math.h>

#define DIM 4096

// R9 structure (256 thr/block, 16 amps/thread, packed-FP32 complex math,
// proven 64 us / absmax 3e-5) with LDS squeezed to EXACTLY 32 KB so 5 blocks
// fit per CU (was 4 at 33792 B): gate matrices move to global scratch
// (computed once by a tiny pre-kernel, read via uniform scalar loads), and
// the reduction scratch aliases the state buffer (only live before the first
// state write / after the last state read).
//   j bits 3..0   = wires 8..11 -> in-register butterflies (packed)
//   lane bits     = wires 2..7  -> cross-lane gates:
//       masks 1,2,8 -> 1 DPP op; mask 4 -> 2 DPP ops (VALU)
//       masks 16,32 -> ds_swizzle / ds_bpermute (DS crossbar, select-free)
//   wave bits     = wires 0..1  -> fused with CNOT chain sigma(i)=i^(i>>1)
//                                  into one LDS 4-partner gather (packed)
// LDS slot swizzle S(i) = i ^ h4((i>>4)&15), h4 = inverse Gray map; write and
// sigma-gather are both bank-conflict-free (measured 0).

typedef float f2 __attribute__((ext_vector_type(2)));

// ---- packed complex primitives (VOP3P op_sel/neg; verified R9) ----
// acc += c*v
__device__ __forceinline__ f2 cfma(f2 acc, f2 c, f2 v) {
  asm("v_pk_fma_f32 %0, %1, %2, %0 op_sel:[0,0,0] op_sel_hi:[0,1,1]\n\t"
      "v_pk_fma_f32 %0, %1, %2, %0 op_sel:[1,1,0] op_sel_hi:[1,0,1] neg_lo:[1,0,0]"
      : "+&v"(acc) : "v"(c), "v"(v));
  return acc;
}
// acc += conj(c)*v
__device__ __forceinline__ f2 cfma_cj(f2 acc, f2 c, f2 v) {
  asm("v_pk_fma_f32 %0, %1, %2, %0 op_sel:[0,0,0] op_sel_hi:[0,1,1]\n\t"
      "v_pk_fma_f32 %0, %1, %2, %0 op_sel:[1,1,0] op_sel_hi:[1,0,1] neg_hi:[1,0,0]"
      : "+&v"(acc) : "v"(c), "v"(v));
  return acc;
}
// d = c*v
__device__ __forceinline__ f2 cmul(f2 c, f2 v) {
  f2 d;
  asm("v_pk_mul_f32 %0, %1, %2 op_sel:[0,0] op_sel_hi:[0,1]\n\t"
      "v_pk_fma_f32 %0, %1, %2, %0 op_sel:[1,1,0] op_sel_hi:[1,0,1] neg_lo:[1,0,0]"
      : "=&v"(d) : "v"(c), "v"(v));
  return d;
}
// d = -conj(c)*v
__device__ __forceinline__ f2 cmul_ncj(f2 c, f2 v) {
  f2 d;
  asm("v_pk_mul_f32 %0, %1, %2 op_sel:[0,0] op_sel_hi:[0,1] neg_lo:[1,0] neg_hi:[1,0]\n\t"
      "v_pk_fma_f32 %0, %1, %2, %0 op_sel:[1,1,0] op_sel_hi:[1,0,1] neg_lo:[1,0,0]"
      : "=&v"(d) : "v"(c), "v"(v));
  return d;
}

__device__ __forceinline__ int h4(int x) {
  return (x ^ (x >> 1) ^ (x >> 2) ^ (x >> 3)) & 15;
}

// Cross-lane exchange of x with lane^M partner.
template<int M>
__device__ __forceinline__ float xch(float x, int paddr) {
  int xi = __float_as_int(x);
  if constexpr (M == 1) {        // quad_perm [1,0,3,2]
    return __int_as_float(__builtin_amdgcn_mov_dpp(xi, 0xB1, 0xF, 0xF, false));
  } else if constexpr (M == 2) { // quad_perm [2,3,0,1]
    return __int_as_float(__builtin_amdgcn_mov_dpp(xi, 0x4E, 0xF, 0xF, false));
  } else if constexpr (M == 4) {
    // banks 0,2 need src[i+4] -> row_shl:4; banks 1,3 need src[i-4] -> row_shr:4
    int r = __builtin_amdgcn_update_dpp(xi, xi, 0x104, 0xF, 0x5, false);
    r     = __builtin_amdgcn_update_dpp(r,  xi, 0x114, 0xF, 0xA, false);
    return __int_as_float(r);
  } else if constexpr (M == 8) { // row_ror:8 == xor 8 within 16-lane row
    return __int_as_float(__builtin_amdgcn_mov_dpp(xi, 0x128, 0xF, 0xF, false));
  } else if constexpr (M == 16) { // xor-16 via LDS crossbar (BitMode)
    return __int_as_float(__builtin_amdgcn_ds_swizzle(xi, 0x401F));
  } else {                       // M == 32: cross-half via bpermute
    return __int_as_float(__builtin_amdgcn_ds_bpermute(paddr, xi));
  }
}

template<int M>
__device__ __forceinline__ void lane_gate(float4 g, int t, int paddr,
                                          f2* __restrict__ z) {
  const bool hi = (t & M) != 0;
  const float sgn = hi ? -1.f : 1.f;
  const f2 c1 = { g.x, sgn * g.y };
  const f2 c2 = { sgn * g.z, g.w };
  #pragma unroll
  for (int p = 0; p < 16; ++p) {
    f2 pp;
    pp.x = xch<M>(z[p].x, paddr);
    pp.y = xch<M>(z[p].y, paddr);
    z[p] = cfma(cmul(c1, z[p]), c2, pp);
  }
}

// ---- pre-kernel: fused gate matrices M = RZ@RY@RX = [[a,b],[-conj(b),conj(a)]]
__global__ void prep_gates(const float* __restrict__ params,
                           float4* __restrict__ ga) {
  const int t = threadIdx.x;
  if (t < 36) {
    const float* P = params + t * 3;
    float hx = P[0]*0.5f, hy = P[1]*0.5f, hz = P[2]*0.5f;
    float cx = cosf(hx), sx = sinf(hx);
    float cy = cosf(hy), sy = sinf(hy);
    float cz = cosf(hz), sz = sinf(hz);
    float arr = cy*cx, aii = sy*sx, brr = sy*cx, bii = cy*sx;
    ga[t] = make_float4(cz*arr + sz*aii,
                        cz*aii - sz*arr,
                        -(cz*brr + sz*bii),
                        -(cz*bii - sz*brr));
  }
}

// ---- main kernel: LDS = st2 only (32768 B exactly -> 5 blocks/CU) ----
__global__ __launch_bounds__(256)
void qsim_kernel(const float* __restrict__ in, const float4* __restrict__ ga4,
                 const float* __restrict__ hw, const float* __restrict__ hb,
                 float* __restrict__ out) {
  __shared__ f2 st2[DIM];                 // 32 KB, swizzled slots
  float* red = reinterpret_cast<float*>(st2);  // alias: live only outside
                                               // the st2-live window

  const int t = threadIdx.x;
  const int b = blockIdx.x;

  // ---- load 16 consecutive amps + block-wide norm ----
  float ld[16];
  const float* inb = in + (size_t)b * DIM + t * 16;
  float ss = 0.f;
  #pragma unroll
  for (int q = 0; q < 4; ++q) {
    float4 v = reinterpret_cast<const float4*>(inb)[q];
    ld[4*q+0]=v.x; ld[4*q+1]=v.y; ld[4*q+2]=v.z; ld[4*q+3]=v.w;
    ss += v.x*v.x + v.y*v.y + v.z*v.z + v.w*v.w;
  }
  #pragma unroll
  for (int o = 1; o < 64; o <<= 1) ss += __shfl_xor(ss, o, 64);
  if ((t & 63) == 0) red[t >> 6] = ss;
  __syncthreads();
  float inv = 1.0f / sqrtf(red[0] + red[1] + red[2] + red[3]);
  __syncthreads();               // red consumed before st2 overwrites it
  f2 z[16];
  #pragma unroll
  for (int j = 0; j < 16; ++j) z[j] = (f2){ ld[j] * inv, 0.f };

  // thread-constant addressing (all GF(2)-linear in i)
  const int wbase = (t << 4) ^ h4(t & 15);          // write slot = wbase ^ j
  const int sig   = (t << 4) ^ (t << 3);            // sigma(i) thread part
  const int sigc  = sig & 1023;                     // bits 11,10 cleared
  const int gb    = sigc ^ h4((sigc >> 4) & 15);    // gather slot = gb ^ gray(j) + y*1024
  const int x11   = (t >> 7) & 1;                   // sigma(i) bit 11 (wire 0)
  const int x10   = ((t >> 6) ^ (t >> 7)) & 1;      // sigma(i) bit 10 (wire 1)
  const int paddr = ((t ^ 32) & 63) << 2;           // bpermute addr for mask 32

  #pragma unroll 1
  for (int L = 0; L < 3; ++L) {
    // ---- 4 register gates: wires 8..11, mask on j (packed butterflies) ----
    #pragma unroll
    for (int w = 8; w <= 11; ++w) {
      const int m = 1 << (11 - w);
      float4 g = ga4[L*12 + w];
      const f2 a  = { g.x, g.y };
      const f2 bb = { g.z, g.w };
      #pragma unroll
      for (int p = 0; p < 16; ++p) {
        if (!(p & m)) {
          const int k2 = p | m;
          f2 v0 = z[p], v1 = z[k2];
          z[p]  = cfma(cmul(a, v0), bb, v1);        // a*v0 + b*v1
          z[k2] = cfma_cj(cmul_ncj(bb, v0), a, v1); // -conj(b)*v0 + conj(a)*v1
        }
      }
    }
    // ---- 6 lane gates: wires 2..7 -> masks 32,16,8,4,2,1 ----
    lane_gate<32>(ga4[L*12 + 2], t, paddr, z);
    lane_gate<16>(ga4[L*12 + 3], t, paddr, z);
    lane_gate< 8>(ga4[L*12 + 4], t, paddr, z);
    lane_gate< 4>(ga4[L*12 + 5], t, paddr, z);
    lane_gate< 2>(ga4[L*12 + 6], t, paddr, z);
    lane_gate< 1>(ga4[L*12 + 7], t, paddr, z);

    // ---- write post-(wires 2..11) state (conflict-free swizzled) ----
    #pragma unroll
    for (int j = 0; j < 16; ++j) st2[wbase ^ j] = z[j];
    __syncthreads();

    // ---- fused: wave gates (wires 0,1) + CNOT chain, 4-partner gather ----
    // new[i] = sum_y G0[x11][y>>1]*G1[x10][y&1] * mid[sigma(i) w/ bits11,10 := y]
    float4 g0 = ga4[L*12 + 0], g1 = ga4[L*12 + 1];
    f2 U0, U1, V0, V1;
    if (x11) { U0 = (f2){-g0.z, g0.w}; U1 = (f2){g0.x, -g0.y}; }
    else     { U0 = (f2){ g0.x, g0.y}; U1 = (f2){g0.z,  g0.w}; }
    if (x10) { V0 = (f2){-g1.z, g1.w}; V1 = (f2){g1.x, -g1.y}; }
    else     { V0 = (f2){ g1.x, g1.y}; V1 = (f2){g1.z,  g1.w}; }
    const f2 c0 = cmul(U0, V0);
    const f2 c1 = cmul(U0, V1);
    const f2 c2 = cmul(U1, V0);
    const f2 c3 = cmul(U1, V1);
    #pragma unroll
    for (int j = 0; j < 16; ++j) {
      const int base = gb ^ (j ^ (j >> 1));
      f2 m0 = st2[base];
      f2 m1 = st2[base + 1024];
      f2 m2 = st2[base + 2048];
      f2 m3 = st2[base + 3072];
      z[j] = cfma(cfma(cfma(cmul(c0, m0), c1, m1), c2, m2), c3, m3);
    }
    if (L != 2) __syncthreads();  // WAR guard between layers
  }

  // ---- readout: sum |amp|^2 * c(i), i = t*16 + j (regs hold final state) ----
  float Ct = 0.f;
  #pragma unroll
  for (int p = 0; p < 8; ++p) Ct += hw[7-p] * (((t >> p) & 1) ? -1.f : 1.f);
  float h11 = hw[11], h10 = hw[10], h9 = hw[9], h8 = hw[8];
  float acc = 0.f;
  #pragma unroll
  for (int j = 0; j < 16; ++j) {
    float pj = z[j].x*z[j].x + z[j].y*z[j].y;
    float cj = Ct + ((j&1) ? -h11 : h11) + ((j&2) ? -h10 : h10)
             + ((j&4) ? -h9  : h9 ) + ((j&8) ? -h8  : h8 );
    acc += pj * cj;
  }
  #pragma unroll
  for (int o = 1; o < 64; o <<= 1) acc += __shfl_xor(acc, o, 64);
  __syncthreads();               // all waves done reading st2 before red alias
  if ((t & 63) == 0) red[t >> 6] = acc;
  __syncthreads();
  if (t == 0) out[b] = red[0] + red[1] + red[2] + red[3] + hb[0];
}

// ---- fallback (exact R9, ga4 in LDS) if d_ws is too small ----
__global__ __launch_bounds__(256)
void qsim_fb(const float* __restrict__ in, const float* __restrict__ params,
             const float* __restrict__ hw, const float* __restrict__ hb,
             float* __restrict__ out) {
  __shared__ f2 st2[DIM];
  __shared__ float4 ga4[36];
  __shared__ float red[4];
  const int t = threadIdx.x;
  const int b = blockIdx.x;
  if (t < 36) {
    const float* P = params + t * 3;
    float hx = P[0]*0.5f, hy = P[1]*0.5f, hz = P[2]*0.5f;
    float cx = cosf(hx), sx = sinf(hx);
    float cy = cosf(hy), sy = sinf(hy);
    float cz = cosf(hz), sz = sinf(hz);
    float arr = cy*cx, aii = sy*sx, brr = sy*cx, bii = cy*sx;
    ga4[t] = make_float4(cz*arr + sz*aii, cz*aii - sz*arr,
                         -(cz*brr + sz*bii), -(cz*bii - sz*brr));
  }
  float ld[16];
  const float* inb = in + (size_t)b * DIM + t * 16;
  float ss = 0.f;
  #pragma unroll
  for (int q = 0; q < 4; ++q) {
    float4 v = reinterpret_cast<const float4*>(inb)[q];
    ld[4*q+0]=v.x; ld[4*q+1]=v.y; ld[4*q+2]=v.z; ld[4*q+3]=v.w;
    ss += v.x*v.x + v.y*v.y + v.z*v.z + v.w*v.w;
  }
  #pragma unroll
  for (int o = 1; o < 64; o <<= 1) ss += __shfl_xor(ss, o, 64);
  if ((t & 63) == 0) red[t >> 6] = ss;
  __syncthreads();
  float inv = 1.0f / sqrtf(red[0] + red[1] + red[2] + red[3]);
  f2 z[16];
  #pragma unroll
  for (int j = 0; j < 16; ++j) z[j] = (f2){ ld[j] * inv, 0.f };
  const int wbase = (t << 4) ^ h4(t & 15);
  const int sig   = (t << 4) ^ (t << 3);
  const int sigc  = sig & 1023;
  const int gb    = sigc ^ h4((sigc >> 4) & 15);
  const int x11   = (t >> 7) & 1;
  const int x10   = ((t >> 6) ^ (t >> 7)) & 1;
  const int paddr = ((t ^ 32) & 63) << 2;
  #pragma unroll 1
  for (int L = 0; L < 3; ++L) {
    #pragma unroll
    for (int w = 8; w <= 11; ++w) {
      const int m = 1 << (11 - w);
      float4 g = ga4[L*12 + w];
      const f2 a = { g.x, g.y };
      const f2 bb = { g.z, g.w };
      #pragma unroll
      for (int p = 0; p < 16; ++p) {
        if (!(p & m)) {
          const int k2 = p | m;
          f2 v0 = z[p], v1 = z[k2];
          z[p]  = cfma(cmul(a, v0), bb, v1);
          z[k2] = cfma_cj(cmul_ncj(bb, v0), a, v1);
        }
      }
    }
    lane_gate<32>(ga4[L*12 + 2], t, paddr, z);
    lane_gate<16>(ga4[L*12 + 3], t, paddr, z);
    lane_gate< 8>(ga4[L*12 + 4], t, paddr, z);
    lane_gate< 4>(ga4[L*12 + 5], t, paddr, z);
    lane_gate< 2>(ga4[L*12 + 6], t, paddr, z);
    lane_gate< 1>(ga4[L*12 + 7], t, paddr, z);
    #pragma unroll
    for (int j = 0; j < 16; ++j) st2[wbase ^ j] = z[j];
    __syncthreads();
    float4 g0 = ga4[L*12 + 0], g1 = ga4[L*12 + 1];
    f2 U0, U1, V0, V1;
    if (x11) { U0 = (f2){-g0.z, g0.w}; U1 = (f2){g0.x, -g0.y}; }
    else     { U0 = (f2){ g0.x, g0.y}; U1 = (f2){g0.z,  g0.w}; }
    if (x10) { V0 = (f2){-g1.z, g1.w}; V1 = (f2){g1.x, -g1.y}; }
    else     { V0 = (f2){ g1.x, g1.y}; V1 = (f2){g1.z,  g1.w}; }
    const f2 c0 = cmul(U0, V0), c1 = cmul(U0, V1);
    const f2 c2 = cmul(U1, V0), c3 = cmul(U1, V1);
    #pragma unroll
    for (int j = 0; j < 16; ++j) {
      const int base = gb ^ (j ^ (j >> 1));
      f2 m0 = st2[base];
      f2 m1 = st2[base + 1024];
      f2 m2 = st2[base + 2048];
      f2 m3 = st2[base + 3072];
      z[j] = cfma(cfma(cfma(cmul(c0, m0), c1, m1), c2, m2), c3, m3);
    }
    if (L != 2) __syncthreads();
  }
  float Ct = 0.f;
  #pragma unroll
  for (int p = 0; p < 8; ++p) Ct += hw[7-p] * (((t >> p) & 1) ? -1.f : 1.f);
  float h11 = hw[11], h10 = hw[10], h9 = hw[9], h8 = hw[8];
  float acc = 0.f;
  #pragma unroll
  for (int j = 0; j < 16; ++j) {
    float pj = z[j].x*z[j].x + z[j].y*z[j].y;
    float cj = Ct + ((j&1) ? -h11 : h11) + ((j&2) ? -h10 : h10)
             + ((j&4) ? -h9  : h9 ) + ((j&8) ? -h8  : h8 );
    acc += pj * cj;
  }
  #pragma unroll
  for (int o = 1; o < 64; o <<= 1) acc += __shfl_xor(acc, o, 64);
  if ((t & 63) == 0) red[t >> 6] = acc;
  __syncthreads();
  if (t == 0) out[b] = red[0] + red[1] + red[2] + red[3] + hb[0];
}

extern "C" void kernel_launch(void* const* d_in, const int* in_sizes, int n_in,
                              void* d_out, int out_size, void* d_ws, size_t ws_size,
                              hipStream_t stream) {
  const float* st     = (const float*)d_in[0];
  const float* params = (const float*)d_in[1];
  const float* hwp    = (const float*)d_in[2];
  const float* hbp    = (const float*)d_in[3];
  float* outp = (float*)d_out;
  int batch = in_sizes[0] / DIM;
  if (ws_size >= 36 * sizeof(float4)) {
    prep_gates<<<1, 64, 0, stream>>>(params, (float4*)d_ws);
    qsim_kernel<<<batch, 256, 0, stream>>>(st, (const float4*)d_ws, hwp, hbp, outp);
  } else {
    qsim_fb<<<batch, 256, 0, stream>>>(st, params, hwp, hbp, outp);
  }
}

// Round 12
// 63.630 us; speedup vs baseline: 1.1526x; 1.0691x over previous
//
#include <hip/hip_runtime.h>
#include <math.h>

#define DIM 4096

// R9 structure (256 thr/block, 16 amps/thread, packed-FP32, single kernel,
// proven 64 us / absmax 3e-5) + explicit DS batch-issue:
//  - DS-based lane gates (masks 4,16,32 via ds_swizzle/ds_bpermute) issue all
//    32 exchanges into a temp array BEFORE the combine loop -> one amortized
//    lgkmcnt wait instead of 16 serialized ones (compiler's min-VGPR schedule
//    was serializing: VGPR_Count=48).
//  - sigma-gather loads batched 4 outputs (16 reads) at a time.
//  - mask 4 moved from 2 DPP VALU ops to 1 batched ds_swizzle (xor-4 BitMode).
// Amp index i = t*16 + j:
//   j bits 3..0   = wires 8..11 -> in-register butterflies (packed pk math)
//   lane bits     = wires 2..7  -> masks 32,16,4 DS-batched; 8,2,1 DPP
//   wave bits     = wires 0..1  -> fused with CNOT chain sigma(i)=i^(i>>1)
//                                  into one LDS 4-partner gather
// LDS slot swizzle S(i) = i ^ h4((i>>4)&15), h4 = inverse Gray map; write and
// sigma-gather are both bank-conflict-free (measured 0).

typedef float f2 __attribute__((ext_vector_type(2)));

// ---- packed complex primitives (VOP3P op_sel/neg; verified R9) ----
// acc += c*v
__device__ __forceinline__ f2 cfma(f2 acc, f2 c, f2 v) {
  asm("v_pk_fma_f32 %0, %1, %2, %0 op_sel:[0,0,0] op_sel_hi:[0,1,1]\n\t"
      "v_pk_fma_f32 %0, %1, %2, %0 op_sel:[1,1,0] op_sel_hi:[1,0,1] neg_lo:[1,0,0]"
      : "+&v"(acc) : "v"(c), "v"(v));
  return acc;
}
// acc += conj(c)*v
__device__ __forceinline__ f2 cfma_cj(f2 acc, f2 c, f2 v) {
  asm("v_pk_fma_f32 %0, %1, %2, %0 op_sel:[0,0,0] op_sel_hi:[0,1,1]\n\t"
      "v_pk_fma_f32 %0, %1, %2, %0 op_sel:[1,1,0] op_sel_hi:[1,0,1] neg_hi:[1,0,0]"
      : "+&v"(acc) : "v"(c), "v"(v));
  return acc;
}
// d = c*v
__device__ __forceinline__ f2 cmul(f2 c, f2 v) {
  f2 d;
  asm("v_pk_mul_f32 %0, %1, %2 op_sel:[0,0] op_sel_hi:[0,1]\n\t"
      "v_pk_fma_f32 %0, %1, %2, %0 op_sel:[1,1,0] op_sel_hi:[1,0,1] neg_lo:[1,0,0]"
      : "=&v"(d) : "v"(c), "v"(v));
  return d;
}
// d = -conj(c)*v
__device__ __forceinline__ f2 cmul_ncj(f2 c, f2 v) {
  f2 d;
  asm("v_pk_mul_f32 %0, %1, %2 op_sel:[0,0] op_sel_hi:[0,1] neg_lo:[1,0] neg_hi:[1,0]\n\t"
      "v_pk_fma_f32 %0, %1, %2, %0 op_sel:[1,1,0] op_sel_hi:[1,0,1] neg_lo:[1,0,0]"
      : "=&v"(d) : "v"(c), "v"(v));
  return d;
}

__device__ __forceinline__ int h4(int x) {
  return (x ^ (x >> 1) ^ (x >> 2) ^ (x >> 3)) & 15;
}

// Cross-lane exchange of x with lane^M partner.
template<int M>
__device__ __forceinline__ float xch(float x, int paddr) {
  int xi = __float_as_int(x);
  if constexpr (M == 1) {        // quad_perm [1,0,3,2]
    return __int_as_float(__builtin_amdgcn_mov_dpp(xi, 0xB1, 0xF, 0xF, false));
  } else if constexpr (M == 2) { // quad_perm [2,3,0,1]
    return __int_as_float(__builtin_amdgcn_mov_dpp(xi, 0x4E, 0xF, 0xF, false));
  } else if constexpr (M == 4) { // xor-4 via LDS crossbar (BitMode)
    return __int_as_float(__builtin_amdgcn_ds_swizzle(xi, 0x101F));
  } else if constexpr (M == 8) { // row_ror:8 == xor 8 within 16-lane row
    return __int_as_float(__builtin_amdgcn_mov_dpp(xi, 0x128, 0xF, 0xF, false));
  } else if constexpr (M == 16) { // xor-16 via LDS crossbar (BitMode)
    return __int_as_float(__builtin_amdgcn_ds_swizzle(xi, 0x401F));
  } else {                       // M == 32: cross-half via bpermute
    return __int_as_float(__builtin_amdgcn_ds_bpermute(paddr, xi));
  }
}

// VALU (DPP) gate: per-value exchange+combine (no memory latency to hide).
template<int M>
__device__ __forceinline__ void lane_gate_dpp(float4 g, int t,
                                              f2* __restrict__ z) {
  const bool hi = (t & M) != 0;
  const float sgn = hi ? -1.f : 1.f;
  const f2 c1 = { g.x, sgn * g.y };
  const f2 c2 = { sgn * g.z, g.w };
  #pragma unroll
  for (int p = 0; p < 16; ++p) {
    f2 pp;
    pp.x = xch<M>(z[p].x, 0);
    pp.y = xch<M>(z[p].y, 0);
    z[p] = cfma(cmul(c1, z[p]), c2, pp);
  }
}

// DS gate: batch-issue ALL 32 exchanges, then combine (one amortized wait).
template<int M>
__device__ __forceinline__ void lane_gate_ds(float4 g, int t, int paddr,
                                             f2* __restrict__ z) {
  const bool hi = (t & M) != 0;
  const float sgn = hi ? -1.f : 1.f;
  const f2 c1 = { g.x, sgn * g.y };
  const f2 c2 = { sgn * g.z, g.w };
  f2 pp[16];
  #pragma unroll
  for (int p = 0; p < 16; ++p) {
    pp[p].x = xch<M>(z[p].x, paddr);
    pp[p].y = xch<M>(z[p].y, paddr);
  }
  #pragma unroll
  for (int p = 0; p < 16; ++p)
    z[p] = cfma(cmul(c1, z[p]), c2, pp[p]);
}

__global__ __launch_bounds__(256)
void qsim_kernel(const float* __restrict__ in, const float* __restrict__ params,
                 const float* __restrict__ hw, const float* __restrict__ hb,
                 float* __restrict__ out) {
  __shared__ f2 st2[DIM];        // 32 KB, swizzled slots
  __shared__ float4 ga4[36];     // fused RZ@RY@RX: (a.re, a.im, b.re, b.im)
  __shared__ float red[4];

  const int t = threadIdx.x;
  const int b = blockIdx.x;

  // Fused gate matrices M = RZ@RY@RX = [[a,b],[-conj(b),conj(a)]]
  if (t < 36) {
    const float* P = params + t * 3;
    float hx = P[0]*0.5f, hy = P[1]*0.5f, hz = P[2]*0.5f;
    float cx = cosf(hx), sx = sinf(hx);
    float cy = cosf(hy), sy = sinf(hy);
    float cz = cosf(hz), sz = sinf(hz);
    float arr = cy*cx, aii = sy*sx, brr = sy*cx, bii = cy*sx;
    ga4[t] = make_float4(cz*arr + sz*aii,
                         cz*aii - sz*arr,
                         -(cz*brr + sz*bii),
                         -(cz*bii - sz*brr));
  }

  // ---- load 16 consecutive amps + block-wide norm ----
  float ld[16];
  const float* inb = in + (size_t)b * DIM + t * 16;
  float ss = 0.f;
  #pragma unroll
  for (int q = 0; q < 4; ++q) {
    float4 v = reinterpret_cast<const float4*>(inb)[q];
    ld[4*q+0]=v.x; ld[4*q+1]=v.y; ld[4*q+2]=v.z; ld[4*q+3]=v.w;
    ss += v.x*v.x + v.y*v.y + v.z*v.z + v.w*v.w;
  }
  #pragma unroll
  for (int o = 1; o < 64; o <<= 1) ss += __shfl_xor(ss, o, 64);
  if ((t & 63) == 0) red[t >> 6] = ss;
  __syncthreads();               // also publishes ga4
  float inv = 1.0f / sqrtf(red[0] + red[1] + red[2] + red[3]);
  f2 z[16];
  #pragma unroll
  for (int j = 0; j < 16; ++j) z[j] = (f2){ ld[j] * inv, 0.f };

  // thread-constant addressing (all GF(2)-linear in i)
  const int wbase = (t << 4) ^ h4(t & 15);          // write slot = wbase ^ j
  const int sig   = (t << 4) ^ (t << 3);            // sigma(i) thread part
  const int sigc  = sig & 1023;                     // bits 11,10 cleared
  const int gb    = sigc ^ h4((sigc >> 4) & 15);    // gather slot = gb ^ gray(j) + y*1024
  const int x11   = (t >> 7) & 1;                   // sigma(i) bit 11 (wire 0)
  const int x10   = ((t >> 6) ^ (t >> 7)) & 1;      // sigma(i) bit 10 (wire 1)
  const int paddr = ((t ^ 32) & 63) << 2;           // bpermute addr for mask 32

  #pragma unroll 1
  for (int L = 0; L < 3; ++L) {
    // ---- 4 register gates: wires 8..11, mask on j (packed butterflies) ----
    #pragma unroll
    for (int w = 8; w <= 11; ++w) {
      const int m = 1 << (11 - w);
      float4 g = ga4[L*12 + w];
      const f2 a  = { g.x, g.y };
      const f2 bb = { g.z, g.w };
      #pragma unroll
      for (int p = 0; p < 16; ++p) {
        if (!(p & m)) {
          const int k2 = p | m;
          f2 v0 = z[p], v1 = z[k2];
          z[p]  = cfma(cmul(a, v0), bb, v1);        // a*v0 + b*v1
          z[k2] = cfma_cj(cmul_ncj(bb, v0), a, v1); // -conj(b)*v0 + conj(a)*v1
        }
      }
    }
    // ---- 6 lane gates: wires 2..7 -> masks 32,16,8,4,2,1 ----
    lane_gate_ds <32>(ga4[L*12 + 2], t, paddr, z);
    lane_gate_ds <16>(ga4[L*12 + 3], t, paddr, z);
    lane_gate_dpp< 8>(ga4[L*12 + 4], t, z);
    lane_gate_ds < 4>(ga4[L*12 + 5], t, paddr, z);
    lane_gate_dpp< 2>(ga4[L*12 + 6], t, z);
    lane_gate_dpp< 1>(ga4[L*12 + 7], t, z);

    // ---- write post-(wires 2..11) state (conflict-free swizzled) ----
    #pragma unroll
    for (int j = 0; j < 16; ++j) st2[wbase ^ j] = z[j];
    __syncthreads();

    // ---- fused: wave gates (wires 0,1) + CNOT chain, 4-partner gather ----
    // new[i] = sum_y G0[x11][y>>1]*G1[x10][y&1] * mid[sigma(i) w/ bits11,10 := y]
    float4 g0 = ga4[L*12 + 0], g1 = ga4[L*12 + 1];
    f2 U0, U1, V0, V1;
    if (x11) { U0 = (f2){-g0.z, g0.w}; U1 = (f2){g0.x, -g0.y}; }
    else     { U0 = (f2){ g0.x, g0.y}; U1 = (f2){g0.z,  g0.w}; }
    if (x10) { V0 = (f2){-g1.z, g1.w}; V1 = (f2){g1.x, -g1.y}; }
    else     { V0 = (f2){ g1.x, g1.y}; V1 = (f2){g1.z,  g1.w}; }
    const f2 c0 = cmul(U0, V0);
    const f2 c1 = cmul(U0, V1);
    const f2 c2 = cmul(U1, V0);
    const f2 c3 = cmul(U1, V1);
    // batched: 16 reads in flight per 4-output group
    #pragma unroll
    for (int jb = 0; jb < 16; jb += 4) {
      f2 m0[4], m1[4], m2[4], m3[4];
      #pragma unroll
      for (int dj = 0; dj < 4; ++dj) {
        const int jj = jb + dj;
        const int base = gb ^ (jj ^ (jj >> 1));
        m0[dj] = st2[base];
        m1[dj] = st2[base + 1024];
        m2[dj] = st2[base + 2048];
        m3[dj] = st2[base + 3072];
      }
      #pragma unroll
      for (int dj = 0; dj < 4; ++dj)
        z[jb+dj] = cfma(cfma(cfma(cmul(c0, m0[dj]), c1, m1[dj]), c2, m2[dj]),
                        c3, m3[dj]);
    }
    if (L != 2) __syncthreads();  // WAR guard between layers
  }

  // ---- readout: sum |amp|^2 * c(i), i = t*16 + j (regs hold final state) ----
  float Ct = 0.f;
  #pragma unroll
  for (int p = 0; p < 8; ++p) Ct += hw[7-p] * (((t >> p) & 1) ? -1.f : 1.f);
  float h11 = hw[11], h10 = hw[10], h9 = hw[9], h8 = hw[8];
  float acc = 0.f;
  #pragma unroll
  for (int j = 0; j < 16; ++j) {
    float pj = z[j].x*z[j].x + z[j].y*z[j].y;
    float cj = Ct + ((j&1) ? -h11 : h11) + ((j&2) ? -h10 : h10)
             + ((j&4) ? -h9  : h9 ) + ((j&8) ? -h8  : h8 );
    acc += pj * cj;
  }
  #pragma unroll
  for (int o = 1; o < 64; o <<= 1) acc += __shfl_xor(acc, o, 64);
  if ((t & 63) == 0) red[t >> 6] = acc;
  __syncthreads();
  if (t == 0) out[b] = red[0] + red[1] + red[2] + red[3] + hb[0];
}

extern "C" void kernel_launch(void* const* d_in, const int* in_sizes, int n_in,
                              void* d_out, int out_size, void* d_ws, size_t ws_size,
                              hipStream_t stream) {
  const float* st     = (const float*)d_in[0];
  const float* params = (const float*)d_in[1];
  const float* hwp    = (const float*)d_in[2];
  const float* hbp    = (const float*)d_in[3];
  float* outp = (float*)d_out;
  int batch = in_sizes[0] / DIM;
  qsim_kernel<<<batch, 256, 0, stream>>>(st, params, hwp, hbp, outp);
}

// Round 13
// 63.374 us; speedup vs baseline: 1.1573x; 1.0040x over previous
//
#include <hip/hip_runtime.h>
#include <math.h>

#define DIM 4096

// 256 thr/block, one block per state, packed-FP32 complex math (R12 base,
// 63.6 us / absmax 3e-5) + two shavings:
//  - deferred normalization: circuit is linear, so out = (sum c|U y|^2)/||y||^2
//    -> no early norm mul/rsqrt/barrier round-trip; ss reduced with acc at end.
//  - mask-8 exchange moved to batched ds_swizzle (VALU is the bottleneck pipe,
//    DS has headroom).
// Amp index i = t*16 + j:
//   j bits 3..0   = wires 8..11 -> in-register butterflies (packed pk math)
//   lane bits     = wires 2..7  -> masks 32(bpermute),16,8,4(swizzle) DS-batched;
//                                  masks 2,1 DPP quad_perm (1 VALU op)
//   wave bits     = wires 0..1  -> fused with CNOT chain sigma(i)=i^(i>>1)
//                                  into one LDS 4-partner gather
// LDS slot swizzle S(i) = i ^ h4((i>>4)&15), h4 = inverse Gray map; write and
// sigma-gather are both bank-conflict-free (measured 0).

typedef float f2 __attribute__((ext_vector_type(2)));

// ---- packed complex primitives (VOP3P op_sel/neg; verified R9-R12) ----
__device__ __forceinline__ f2 cfma(f2 acc, f2 c, f2 v) {   // acc += c*v
  asm("v_pk_fma_f32 %0, %1, %2, %0 op_sel:[0,0,0] op_sel_hi:[0,1,1]\n\t"
      "v_pk_fma_f32 %0, %1, %2, %0 op_sel:[1,1,0] op_sel_hi:[1,0,1] neg_lo:[1,0,0]"
      : "+&v"(acc) : "v"(c), "v"(v));
  return acc;
}
__device__ __forceinline__ f2 cfma_cj(f2 acc, f2 c, f2 v) { // acc += conj(c)*v
  asm("v_pk_fma_f32 %0, %1, %2, %0 op_sel:[0,0,0] op_sel_hi:[0,1,1]\n\t"
      "v_pk_fma_f32 %0, %1, %2, %0 op_sel:[1,1,0] op_sel_hi:[1,0,1] neg_hi:[1,0,0]"
      : "+&v"(acc) : "v"(c), "v"(v));
  return acc;
}
__device__ __forceinline__ f2 cmul(f2 c, f2 v) {            // d = c*v
  f2 d;
  asm("v_pk_mul_f32 %0, %1, %2 op_sel:[0,0] op_sel_hi:[0,1]\n\t"
      "v_pk_fma_f32 %0, %1, %2, %0 op_sel:[1,1,0] op_sel_hi:[1,0,1] neg_lo:[1,0,0]"
      : "=&v"(d) : "v"(c), "v"(v));
  return d;
}
__device__ __forceinline__ f2 cmul_ncj(f2 c, f2 v) {        // d = -conj(c)*v
  f2 d;
  asm("v_pk_mul_f32 %0, %1, %2 op_sel:[0,0] op_sel_hi:[0,1] neg_lo:[1,0] neg_hi:[1,0]\n\t"
      "v_pk_fma_f32 %0, %1, %2, %0 op_sel:[1,1,0] op_sel_hi:[1,0,1] neg_lo:[1,0,0]"
      : "=&v"(d) : "v"(c), "v"(v));
  return d;
}

__device__ __forceinline__ int h4(int x) {
  return (x ^ (x >> 1) ^ (x >> 2) ^ (x >> 3)) & 15;
}

// Cross-lane exchange of x with lane^M partner.
template<int M>
__device__ __forceinline__ float xch(float x, int paddr) {
  int xi = __float_as_int(x);
  if constexpr (M == 1) {        // quad_perm [1,0,3,2]
    return __int_as_float(__builtin_amdgcn_mov_dpp(xi, 0xB1, 0xF, 0xF, false));
  } else if constexpr (M == 2) { // quad_perm [2,3,0,1]
    return __int_as_float(__builtin_amdgcn_mov_dpp(xi, 0x4E, 0xF, 0xF, false));
  } else if constexpr (M == 4) { // xor-4 via LDS crossbar (BitMode)
    return __int_as_float(__builtin_amdgcn_ds_swizzle(xi, 0x101F));
  } else if constexpr (M == 8) { // xor-8 via LDS crossbar (BitMode)
    return __int_as_float(__builtin_amdgcn_ds_swizzle(xi, 0x201F));
  } else if constexpr (M == 16) { // xor-16 via LDS crossbar (BitMode)
    return __int_as_float(__builtin_amdgcn_ds_swizzle(xi, 0x401F));
  } else {                       // M == 32: cross-half via bpermute
    return __int_as_float(__builtin_amdgcn_ds_bpermute(paddr, xi));
  }
}

// DPP gate: per-value exchange+combine (register-only, no latency to hide).
template<int M>
__device__ __forceinline__ void lane_gate_dpp(float4 g, int t,
                                              f2* __restrict__ z) {
  const bool hi = (t & M) != 0;
  const float sgn = hi ? -1.f : 1.f;
  const f2 c1 = { g.x, sgn * g.y };
  const f2 c2 = { sgn * g.z, g.w };
  #pragma unroll
  for (int p = 0; p < 16; ++p) {
    f2 pp;
    pp.x = xch<M>(z[p].x, 0);
    pp.y = xch<M>(z[p].y, 0);
    z[p] = cfma(cmul(c1, z[p]), c2, pp);
  }
}

// DS gate: batch-issue all 32 exchanges, then combine (amortized lgkm wait).
template<int M>
__device__ __forceinline__ void lane_gate_ds(float4 g, int t, int paddr,
                                             f2* __restrict__ z) {
  const bool hi = (t & M) != 0;
  const float sgn = hi ? -1.f : 1.f;
  const f2 c1 = { g.x, sgn * g.y };
  const f2 c2 = { sgn * g.z, g.w };
  f2 pp[16];
  #pragma unroll
  for (int p = 0; p < 16; ++p) {
    pp[p].x = xch<M>(z[p].x, paddr);
    pp[p].y = xch<M>(z[p].y, paddr);
  }
  #pragma unroll
  for (int p = 0; p < 16; ++p)
    z[p] = cfma(cmul(c1, z[p]), c2, pp[p]);
}

__global__ __launch_bounds__(256)
void qsim_kernel(const float* __restrict__ in, const float* __restrict__ params,
                 const float* __restrict__ hw, const float* __restrict__ hb,
                 float* __restrict__ out) {
  __shared__ f2 st2[DIM];        // 32 KB, swizzled slots
  __shared__ float4 ga4[36];     // fused RZ@RY@RX: (a.re, a.im, b.re, b.im)
  __shared__ float red[8];

  const int t = threadIdx.x;
  const int b = blockIdx.x;

  // Fused gate matrices M = RZ@RY@RX = [[a,b],[-conj(b),conj(a)]]
  if (t < 36) {
    const float* P = params + t * 3;
    float hx = P[0]*0.5f, hy = P[1]*0.5f, hz = P[2]*0.5f;
    float cx = cosf(hx), sx = sinf(hx);
    float cy = cosf(hy), sy = sinf(hy);
    float cz = cosf(hz), sz = sinf(hz);
    float arr = cy*cx, aii = sy*sx, brr = sy*cx, bii = cy*sx;
    ga4[t] = make_float4(cz*arr + sz*aii,
                         cz*aii - sz*arr,
                         -(cz*brr + sz*bii),
                         -(cz*bii - sz*brr));
  }

  // ---- load 16 consecutive amps; per-thread sum-of-squares (norm DEFERRED:
  // the circuit is linear, so out = (sum c|U y|^2) / ||y||^2) ----
  f2 z[16];
  const float* inb = in + (size_t)b * DIM + t * 16;
  float ss = 0.f;
  #pragma unroll
  for (int q = 0; q < 4; ++q) {
    float4 v = reinterpret_cast<const float4*>(inb)[q];
    z[4*q+0] = (f2){v.x, 0.f};
    z[4*q+1] = (f2){v.y, 0.f};
    z[4*q+2] = (f2){v.z, 0.f};
    z[4*q+3] = (f2){v.w, 0.f};
    ss += v.x*v.x + v.y*v.y + v.z*v.z + v.w*v.w;
  }

  // thread-constant addressing (all GF(2)-linear in i)
  const int wbase = (t << 4) ^ h4(t & 15);          // write slot = wbase ^ j
  const int sig   = (t << 4) ^ (t << 3);            // sigma(i) thread part
  const int sigc  = sig & 1023;                     // bits 11,10 cleared
  const int gb    = sigc ^ h4((sigc >> 4) & 15);    // gather slot = gb ^ gray(j) + y*1024
  const int x11   = (t >> 7) & 1;                   // sigma(i) bit 11 (wire 0)
  const int x10   = ((t >> 6) ^ (t >> 7)) & 1;      // sigma(i) bit 10 (wire 1)
  const int paddr = ((t ^ 32) & 63) << 2;           // bpermute addr for mask 32

  __syncthreads();               // publishes ga4

  #pragma unroll 1
  for (int L = 0; L < 3; ++L) {
    // ---- 4 register gates: wires 8..11, mask on j (packed butterflies) ----
    #pragma unroll
    for (int w = 8; w <= 11; ++w) {
      const int m = 1 << (11 - w);
      float4 g = ga4[L*12 + w];
      const f2 a  = { g.x, g.y };
      const f2 bb = { g.z, g.w };
      #pragma unroll
      for (int p = 0; p < 16; ++p) {
        if (!(p & m)) {
          const int k2 = p | m;
          f2 v0 = z[p], v1 = z[k2];
          z[p]  = cfma(cmul(a, v0), bb, v1);        // a*v0 + b*v1
          z[k2] = cfma_cj(cmul_ncj(bb, v0), a, v1); // -conj(b)*v0 + conj(a)*v1
        }
      }
    }
    // ---- 6 lane gates: wires 2..7 -> masks 32,16,8,4,2,1 ----
    lane_gate_ds <32>(ga4[L*12 + 2], t, paddr, z);
    lane_gate_ds <16>(ga4[L*12 + 3], t, paddr, z);
    lane_gate_ds < 8>(ga4[L*12 + 4], t, paddr, z);
    lane_gate_ds < 4>(ga4[L*12 + 5], t, paddr, z);
    lane_gate_dpp< 2>(ga4[L*12 + 6], t, z);
    lane_gate_dpp< 1>(ga4[L*12 + 7], t, z);

    // ---- write post-(wires 2..11) state (conflict-free swizzled) ----
    #pragma unroll
    for (int j = 0; j < 16; ++j) st2[wbase ^ j] = z[j];
    __syncthreads();

    // ---- fused: wave gates (wires 0,1) + CNOT chain, 4-partner gather ----
    // new[i] = sum_y G0[x11][y>>1]*G1[x10][y&1] * mid[sigma(i) w/ bits11,10 := y]
    float4 g0 = ga4[L*12 + 0], g1 = ga4[L*12 + 1];
    f2 U0, U1, V0, V1;
    if (x11) { U0 = (f2){-g0.z, g0.w}; U1 = (f2){g0.x, -g0.y}; }
    else     { U0 = (f2){ g0.x, g0.y}; U1 = (f2){g0.z,  g0.w}; }
    if (x10) { V0 = (f2){-g1.z, g1.w}; V1 = (f2){g1.x, -g1.y}; }
    else     { V0 = (f2){ g1.x, g1.y}; V1 = (f2){g1.z,  g1.w}; }
    const f2 c0 = cmul(U0, V0);
    const f2 c1 = cmul(U0, V1);
    const f2 c2 = cmul(U1, V0);
    const f2 c3 = cmul(U1, V1);
    // batched: 16 reads in flight per 4-output group
    #pragma unroll
    for (int jb = 0; jb < 16; jb += 4) {
      f2 m0[4], m1[4], m2[4], m3[4];
      #pragma unroll
      for (int dj = 0; dj < 4; ++dj) {
        const int jj = jb + dj;
        const int base = gb ^ (jj ^ (jj >> 1));
        m0[dj] = st2[base];
        m1[dj] = st2[base + 1024];
        m2[dj] = st2[base + 2048];
        m3[dj] = st2[base + 3072];
      }
      #pragma unroll
      for (int dj = 0; dj < 4; ++dj)
        z[jb+dj] = cfma(cfma(cfma(cmul(c0, m0[dj]), c1, m1[dj]), c2, m2[dj]),
                        c3, m3[dj]);
    }
    if (L != 2) __syncthreads();  // WAR guard between layers
  }

  // ---- readout: (sum |amp|^2 c(i)) / ss_total, i = t*16 + j ----
  float Ct = 0.f;
  #pragma unroll
  for (int p = 0; p < 8; ++p) Ct += hw[7-p] * (((t >> p) & 1) ? -1.f : 1.f);
  float h11 = hw[11], h10 = hw[10], h9 = hw[9], h8 = hw[8];
  float acc = 0.f;
  #pragma unroll
  for (int j = 0; j < 16; ++j) {
    float pj = z[j].x*z[j].x + z[j].y*z[j].y;
    float cj = Ct + ((j&1) ? -h11 : h11) + ((j&2) ? -h10 : h10)
             + ((j&4) ? -h9  : h9 ) + ((j&8) ? -h8  : h8 );
    acc += pj * cj;
  }
  // interleaved dual reduction (acc and deferred-norm ss)
  #pragma unroll
  for (int o = 1; o < 64; o <<= 1) {
    acc += __shfl_xor(acc, o, 64);
    ss  += __shfl_xor(ss,  o, 64);
  }
  if ((t & 63) == 0) { red[t >> 6] = acc; red[4 + (t >> 6)] = ss; }
  __syncthreads();
  if (t == 0) {
    float accT = red[0] + red[1] + red[2] + red[3];
    float ssT  = red[4] + red[5] + red[6] + red[7];
    out[b] = accT / ssT + hb[0];
  }
}

extern "C" void kernel_launch(void* const* d_in, const int* in_sizes, int n_in,
                              void* d_out, int out_size, void* d_ws, size_t ws_size,
                              hipStream_t stream) {
  const float* st     = (const float*)d_in[0];
  const float* params = (const float*)d_in[1];
  const float* hwp    = (const float*)d_in[2];
  const float* hbp    = (const float*)d_in[3];
  float* outp = (float*)d_out;
  int batch = in_sizes[0] / DIM;
  qsim_kernel<<<batch, 256, 0, stream>>>(st, params, hwp, hbp, outp);
}